// Round 1
// baseline (84.819 us; speedup 1.0000x reference)
//
#include <hip/hip_runtime.h>

typedef __attribute__((ext_vector_type(8))) short short8;
typedef __attribute__((ext_vector_type(4))) float floatx4;

#define NB 4096
#define NF 1024
#define NR 64
#define NK 32
#define ND 16
#define HALF_D_LOG2PI 14.702988531274762f

// bf16 helpers (finite values only; round-to-nearest-even)
__device__ __forceinline__ unsigned f2bf_bits(float f) {
    unsigned u = __float_as_uint(f);
    return (u + 0x7fffu + ((u >> 16) & 1u)) >> 16;
}

// ---------------- K1: prep (one block per r) --------------------------------
// K=32 layout. wfrag[(((r*2)+nt)*64 + lane)*8 + j] = bf16 of
//   W[r][kk=nt*16+(lane&15)][K=(lane>>4)*8+j],  K<16 -> A[d=K], K>=16 -> B[d=K-16]
// A = -0.5/s^2 (multiplies x^2), B = m/s^2 (multiplies x).
__global__ __launch_bounds__(256) void prep_kernel(
    const float* __restrict__ means, const float* __restrict__ scales,
    unsigned short* __restrict__ wfrag, float* __restrict__ cv)
{
    __shared__ float Asm[NK][ND];
    __shared__ float Bsm[NK][ND];
    __shared__ float csum[NK][8];
    const int r = blockIdx.x;
    const int t = threadIdx.x;

    {   // A,B and log-det partials: 2 (k,d) elems per thread
        int k  = t >> 3;
        int d0 = (t & 7) * 2;
        const float* m = means  + ((size_t)r * NK + k) * ND + d0;
        const float* s = scales + ((size_t)r * NK + k) * ND + d0;
        float partial = 0.f;
#pragma unroll
        for (int q = 0; q < 2; ++q) {
            float sd = s[q], md = m[q];
            float a  = 1.f / sd;
            float a2 = a * a;
            Asm[k][d0 + q] = -0.5f * a2;
            Bsm[k][d0 + q] = md * a2;
            float c = md * a;
            partial += -0.5f * c * c - logf(sd);
        }
        csum[k][t & 7] = partial;
    }
    __syncthreads();
    if (t < NK) {
        float acc = 0.f;
#pragma unroll
        for (int q = 0; q < 8; ++q) acc += csum[t][q];
        cv[r * NK + t] = acc - HALF_D_LOG2PI;
    }

    if (t < 128) {   // emit this r's 2 KB of B-fragments, coalesced uint4
        const int nt   = t >> 6;
        const int lane = t & 63;
        const int n    = lane & 15;
        const int qd   = lane >> 4;
        const int kk   = nt * 16 + n;
        unsigned px[4];
#pragma unroll
        for (int j2 = 0; j2 < 4; ++j2) {
            int K0 = qd * 8 + j2 * 2;
            int K1 = K0 + 1;
            float v0 = (K0 < 16) ? Asm[kk][K0] : Bsm[kk][K0 - 16];
            float v1 = (K1 < 16) ? Asm[kk][K1] : Bsm[kk][K1 - 16];
            px[j2] = f2bf_bits(v0) | (f2bf_bits(v1) << 16);
        }
        *(uint4*)(wfrag + (((size_t)r * 2 + nt) * 64 + lane) * 8) = *(uint4*)px;
    }
}

// ---------------- K2: fused gather + transform + MFMA (direct-gather) -------
// Grid 512 blocks x 256 threads (4 waves). Block = 16 b-rows x 32 r
// (r-half rh = blockIdx.x & 1; b-tile bt = blockIdx.x >> 1, so the two
// blocks sharing a b-tile are dispatch-adjacent -> x re-read hits L3).
// LDS = xs[16][1028] (65.8 KB) + ridx[32][16] (2 KB) + cvs[32][32] (4 KB)
// = 70.2 KB -> 2 blocks/CU co-resident: phase-1 HBM staging of one block
// overlaps the MFMA/store loop of the other. ONE barrier total.
//
// MFMA A-fragment is gathered per-lane directly from xs: lane (col,quad)
// supplies A[row=col][k=quad*8+j] where k<16 -> x^2[d=k], k>=16 -> x[d=k-16],
// i.e. d-slice (quad&1)*8..+8, squared iff quad<2. Quads (0,2) and (1,3)
// read identical LDS addresses (broadcast, free); within a quad the 16 cols
// map to banks (4*col+idx)%32 -> worst 2-way (free per m136).
__global__ __launch_bounds__(256, 2) void fused_kernel(
    const float* __restrict__ x, const int* __restrict__ regions,
    const unsigned short* __restrict__ wfrag, const float* __restrict__ cv,
    float* __restrict__ out)
{
    __shared__ __align__(16) float xs[16][1028];
    __shared__ __align__(16) int   ridx[32][16];
    __shared__ __align__(16) float cvs[32][32];

    const int t  = threadIdx.x;                   // 0..255
    const int bt = blockIdx.x >> 1;
    const int rh = blockIdx.x & 1;
    const int b0 = bt * 16;
    const int r0 = rh * 32;

    // ---- phase 1: stage x rows, region indices, cv ----
    {
        const float4* src = (const float4*)(x + (size_t)b0 * NF);
#pragma unroll
        for (int i = 0; i < 16; ++i) {
            int j = t + i * 256;                  // 4096 float4 total
            int row = j >> 8, c4 = j & 255;       // row = i, c4 = t (coalesced)
            *(float4*)(&xs[row][c4 * 4]) = src[row * 256 + c4];
        }
    }
    if (t < 128)                                  // 32 r x 16 d indices
        ((int4*)ridx)[t] = ((const int4*)(regions + r0 * ND))[t];
    ((float4*)cvs)[t] = ((const float4*)(cv + r0 * NK))[t];  // 32x32 f32
    __syncthreads();

    // ---- phase 2: per-wave r-loop, direct gather -> MFMA -> store ----
    const int wv   = t >> 6;                      // 0..3, handles r = wv*8..+8
    const int L    = t & 63;
    const int col  = L & 15;
    const int quad = L >> 4;
    const bool sq  = quad < 2;                    // quads 0/1 supply x^2
    const int dsl  = (quad & 1) * 8;              // d-slice base
    const float* xc = &xs[col][0];
    const short* wfs = (const short*)wfrag;

#pragma unroll 2
    for (int i = 0; i < 8; ++i) {
        const int r  = wv * 8 + i;                // local r (0..31)
        const int rg = r0 + r;                    // global r

        int4 i4a = *(const int4*)&ridx[r][dsl];       // broadcast b128
        int4 i4b = *(const int4*)&ridx[r][dsl + 4];
        float v0 = xc[i4a.x], v1 = xc[i4a.y], v2 = xc[i4a.z], v3 = xc[i4a.w];
        float v4 = xc[i4b.x], v5 = xc[i4b.y], v6 = xc[i4b.z], v7 = xc[i4b.w];
        if (sq) {                                 // exec-masked squares
            v0 *= v0; v1 *= v1; v2 *= v2; v3 *= v3;
            v4 *= v4; v5 *= v5; v6 *= v6; v7 *= v7;
        }
        unsigned p[4];
        p[0] = f2bf_bits(v0) | (f2bf_bits(v1) << 16);
        p[1] = f2bf_bits(v2) | (f2bf_bits(v3) << 16);
        p[2] = f2bf_bits(v4) | (f2bf_bits(v5) << 16);
        p[3] = f2bf_bits(v6) | (f2bf_bits(v7) << 16);
        short8 a = *(short8*)p;

        size_t wb = (size_t)rg * 2 * 512 + (size_t)L * 8;
        short8 w0 = *(const short8*)(wfs + wb);          // kk 0..15
        short8 w1 = *(const short8*)(wfs + wb + 512);    // kk 16..31

        floatx4 z = {0.f, 0.f, 0.f, 0.f};
        floatx4 acc0 = __builtin_amdgcn_mfma_f32_16x16x32_bf16(a, w0, z, 0, 0, 0);
        floatx4 acc1 = __builtin_amdgcn_mfma_f32_16x16x32_bf16(a, w1, z, 0, 0, 0);

        float c0 = cvs[r][col];
        float c1 = cvs[r][16 + col];
        int brow = b0 + quad * 4;
#pragma unroll
        for (int g = 0; g < 4; ++g) {
            size_t ob = (size_t)(brow + g) * (NR * NK) + (size_t)rg * NK;
            out[ob + col]      = acc0[g] + c0;
            out[ob + 16 + col] = acc1[g] + c1;
        }
    }
}

extern "C" void kernel_launch(void* const* d_in, const int* in_sizes, int n_in,
                              void* d_out, int out_size, void* d_ws, size_t ws_size,
                              hipStream_t stream) {
    const float* x       = (const float*)d_in[0];
    const int*   regions = (const int*)d_in[1];
    const float* means   = (const float*)d_in[2];
    const float* scales  = (const float*)d_in[3];
    float* out = (float*)d_out;

    char* ws = (char*)d_ws;
    unsigned short* wfrag = (unsigned short*)ws;       // 128 KB
    float*          cvp   = (float*)(ws + 131072);     // 8 KB

    prep_kernel<<<dim3(NR), 256, 0, stream>>>(means, scales, wfrag, cvp);
    fused_kernel<<<dim3((NB / 16) * 2), 256, 0, stream>>>(x, regions, wfrag, cvp, out);
}

// Round 2
// 83.510 us; speedup vs baseline: 1.0157x; 1.0157x over previous
//
#include <hip/hip_runtime.h>

typedef __attribute__((ext_vector_type(8))) short short8;
typedef __attribute__((ext_vector_type(4))) float floatx4;

#define NB 4096
#define NF 1024
#define NR 64
#define NK 32
#define ND 16
#define HALF_D_LOG2PI 14.702988531274762f

typedef unsigned int u32;
typedef __attribute__((address_space(1))) const u32 gu32;
typedef __attribute__((address_space(3))) u32 su32;

// bf16 helpers (finite values only; round-to-nearest-even)
__device__ __forceinline__ unsigned f2bf_bits(float f) {
    unsigned u = __float_as_uint(f);
    return (u + 0x7fffu + ((u >> 16) & 1u)) >> 16;
}

// ---------------- K1: prep (one block per r) --------------------------------
// K=32 layout. wfrag[(((r*2)+nt)*64 + lane)*8 + j] = bf16 of
//   W[r][kk=nt*16+(lane&15)][K=(lane>>4)*8+j],  K<16 -> A[d=K], K>=16 -> B[d=K-16]
// A = -0.5/s^2 (multiplies x^2), B = m/s^2 (multiplies x).
__global__ __launch_bounds__(256) void prep_kernel(
    const float* __restrict__ means, const float* __restrict__ scales,
    unsigned short* __restrict__ wfrag, float* __restrict__ cv)
{
    __shared__ float Asm[NK][ND];
    __shared__ float Bsm[NK][ND];
    __shared__ float csum[NK][8];
    const int r = blockIdx.x;
    const int t = threadIdx.x;

    {   // A,B and log-det partials: 2 (k,d) elems per thread
        int k  = t >> 3;
        int d0 = (t & 7) * 2;
        const float* m = means  + ((size_t)r * NK + k) * ND + d0;
        const float* s = scales + ((size_t)r * NK + k) * ND + d0;
        float partial = 0.f;
#pragma unroll
        for (int q = 0; q < 2; ++q) {
            float sd = s[q], md = m[q];
            float a  = 1.f / sd;
            float a2 = a * a;
            Asm[k][d0 + q] = -0.5f * a2;
            Bsm[k][d0 + q] = md * a2;
            float c = md * a;
            partial += -0.5f * c * c - logf(sd);
        }
        csum[k][t & 7] = partial;
    }
    __syncthreads();
    if (t < NK) {
        float acc = 0.f;
#pragma unroll
        for (int q = 0; q < 8; ++q) acc += csum[t][q];
        cv[r * NK + t] = acc - HALF_D_LOG2PI;
    }

    if (t < 128) {   // emit this r's 2 KB of B-fragments, coalesced uint4
        const int nt   = t >> 6;
        const int lane = t & 63;
        const int n    = lane & 15;
        const int qd   = lane >> 4;
        const int kk   = nt * 16 + n;
        unsigned px[4];
#pragma unroll
        for (int j2 = 0; j2 < 4; ++j2) {
            int K0 = qd * 8 + j2 * 2;
            int K1 = K0 + 1;
            float v0 = (K0 < 16) ? Asm[kk][K0] : Bsm[kk][K0 - 16];
            float v1 = (K1 < 16) ? Asm[kk][K1] : Bsm[kk][K1 - 16];
            px[j2] = f2bf_bits(v0) | (f2bf_bits(v1) << 16);
        }
        *(uint4*)(wfrag + (((size_t)r * 2 + nt) * 64 + lane) * 8) = *(uint4*)px;
    }
}

// ---------------- K2: fused gather + transform + MFMA (direct-gather) -------
// Grid 512 blocks x 256 threads (4 waves). Block = 16 b-rows x 32 r.
// XCD-pair swizzle: logical = (wg&7)*64 + (wg>>3), so the two blocks sharing
// a b-tile (rh=0/1) are consecutive logicals on the SAME XCD -> the duplicate
// 64 KB x-tile read is an L2 hit instead of L3/HBM.
// Phase 1 stages x via global_load_lds width=16 (no VGPR round-trip):
// per wave, rows wv*4..wv*4+3, each row = 4 chunks of 1 KB (64 lanes x 16 B),
// LDS dest wave-uniform base (pad lives BETWEEN rows so each chunk is linear).
// LDS = xs[16][1028] + ridx[32][16] + cvs[32][32] = 70.2 KB -> 2 blocks/CU;
// phase-1 staging of one block overlaps the MFMA loop of the other. 1 barrier.
__global__ __launch_bounds__(256, 2) void fused_kernel(
    const float* __restrict__ x, const int* __restrict__ regions,
    const unsigned short* __restrict__ wfrag, const float* __restrict__ cv,
    float* __restrict__ out)
{
    __shared__ __align__(16) float xs[16][1028];
    __shared__ __align__(16) int   ridx[32][16];
    __shared__ __align__(16) float cvs[32][32];

    const int t   = threadIdx.x;                  // 0..255
    const int wg  = blockIdx.x;
    const int lg  = (wg & 7) * 64 + (wg >> 3);    // bijective XCD-pair swizzle
    const int bt  = lg >> 1;
    const int rh  = lg & 1;
    const int b0  = bt * 16;
    const int r0  = rh * 32;
    const int wv  = t >> 6;                       // wave 0..3
    const int L   = t & 63;

    // ---- phase 1: stage x rows direct-to-LDS, indices, cv ----
#pragma unroll
    for (int rr = 0; rr < 4; ++rr) {
        const int row = wv * 4 + rr;
        const float* gsrc = x + (size_t)(b0 + row) * NF + L * 4;
#pragma unroll
        for (int c = 0; c < 4; ++c) {
            __builtin_amdgcn_global_load_lds(
                (gu32*)(gsrc + c * 256),
                (su32*)(&xs[row][c * 256]),     // wave-uniform base
                16, 0, 0);
        }
    }
    if (t < 128)                                  // 32 r x 16 d indices
        ((int4*)ridx)[t] = ((const int4*)(regions + r0 * ND))[t];
    ((float4*)cvs)[t] = ((const float4*)(cv + r0 * NK))[t];  // 32x32 f32
    __syncthreads();                              // drains vmcnt + lgkm

    // ---- phase 2: per-wave r-loop, direct gather -> MFMA -> store ----
    const int col  = L & 15;
    const int quad = L >> 4;
    const bool sq  = quad < 2;                    // quads 0/1 supply x^2
    const int dsl  = (quad & 1) * 8;              // d-slice base
    const float* xc = &xs[col][0];
    const short* wfs = (const short*)wfrag;

#pragma unroll 2
    for (int i = 0; i < 8; ++i) {
        const int r  = wv * 8 + i;                // local r (0..31)
        const int rg = r0 + r;                    // global r

        int4 i4a = *(const int4*)&ridx[r][dsl];       // broadcast b128
        int4 i4b = *(const int4*)&ridx[r][dsl + 4];
        float v0 = xc[i4a.x], v1 = xc[i4a.y], v2 = xc[i4a.z], v3 = xc[i4a.w];
        float v4 = xc[i4b.x], v5 = xc[i4b.y], v6 = xc[i4b.z], v7 = xc[i4b.w];
        if (sq) {                                 // exec-masked squares
            v0 *= v0; v1 *= v1; v2 *= v2; v3 *= v3;
            v4 *= v4; v5 *= v5; v6 *= v6; v7 *= v7;
        }
        unsigned p[4];
        p[0] = f2bf_bits(v0) | (f2bf_bits(v1) << 16);
        p[1] = f2bf_bits(v2) | (f2bf_bits(v3) << 16);
        p[2] = f2bf_bits(v4) | (f2bf_bits(v5) << 16);
        p[3] = f2bf_bits(v6) | (f2bf_bits(v7) << 16);
        short8 a = *(short8*)p;

        size_t wb = (size_t)rg * 2 * 512 + (size_t)L * 8;
        short8 w0 = *(const short8*)(wfs + wb);          // kk 0..15
        short8 w1 = *(const short8*)(wfs + wb + 512);    // kk 16..31

        floatx4 z = {0.f, 0.f, 0.f, 0.f};
        floatx4 acc0 = __builtin_amdgcn_mfma_f32_16x16x32_bf16(a, w0, z, 0, 0, 0);
        floatx4 acc1 = __builtin_amdgcn_mfma_f32_16x16x32_bf16(a, w1, z, 0, 0, 0);

        float c0 = cvs[r][col];
        float c1 = cvs[r][16 + col];
        int brow = b0 + quad * 4;
#pragma unroll
        for (int g = 0; g < 4; ++g) {
            size_t ob = (size_t)(brow + g) * (NR * NK) + (size_t)rg * NK;
            out[ob + col]      = acc0[g] + c0;
            out[ob + 16 + col] = acc1[g] + c1;
        }
    }
}

extern "C" void kernel_launch(void* const* d_in, const int* in_sizes, int n_in,
                              void* d_out, int out_size, void* d_ws, size_t ws_size,
                              hipStream_t stream) {
    const float* x       = (const float*)d_in[0];
    const int*   regions = (const int*)d_in[1];
    const float* means   = (const float*)d_in[2];
    const float* scales  = (const float*)d_in[3];
    float* out = (float*)d_out;

    char* ws = (char*)d_ws;
    unsigned short* wfrag = (unsigned short*)ws;       // 128 KB
    float*          cvp   = (float*)(ws + 131072);     // 8 KB

    prep_kernel<<<dim3(NR), 256, 0, stream>>>(means, scales, wfrag, cvp);
    fused_kernel<<<dim3((NB / 16) * 2), 256, 0, stream>>>(x, regions, wfrag, cvp, out);
}